// Round 4
// baseline (222.162 us; speedup 1.0000x reference)
//
#include <hip/hip_runtime.h>
#include <math.h>
#include <limits.h>

#define BB 128
#define KK 2048
#define NN 4
#define CC 64
#define DD 3
#define SL 8            // K-slices per batch
#define KS (KK/SL)      // 256 k per slice
#define THREADS 256

// ws layout (float words):
#define OFF_CVAL 0
#define OFF_CIDX (BB*SL*NN*NN)
#define OFF_OBJ  (2*BB*SL*NN*NN)
#define OFF_PART (OFF_OBJ + BB*SL)
#define OFF_CNT  (OFF_PART + BB*3)     // BB batch counters + 1 global counter (ints)

// ---- fast approximations: COST MATRIX ONLY (losses use accurate libm) ----
__device__ __forceinline__ float acospi_fast(float x) {
    // Hastings: acos(x) ~ sqrt(1-x)*p(x), abs err ~6.7e-5 rad; divided by pi.
    float ax = fabsf(x);
    float p = ((-0.0187293f*ax + 0.0742610f)*ax - 0.2121144f)*ax + 1.5707288f;
    float r = sqrtf(1.f - ax) * p;
    r = (x >= 0.f) ? r : 3.14159274f - r;
    return r * 0.31830988618379067f;
}

__global__ void __launch_bounds__(THREADS)
crit_fused(const float* __restrict__ loc_out, const float* __restrict__ obj_logit,
           const float* __restrict__ cls_logit, const float* __restrict__ gt_loc,
           const float* __restrict__ gt_cls, float* __restrict__ ws,
           float* __restrict__ out)
{
    __shared__ float s_vt[NN][DD];
    __shared__ float s_pos[NN];
    __shared__ int   s_cls[NN];
    __shared__ float cost[NN][KS];     // 4 KB
    __shared__ float obj_s[4];
    __shared__ int   s_flag;
    __shared__ float cand_val[NN][NN];
    __shared__ int   cand_idx[NN][NN];
    __shared__ int   s_pred[NN];
    __shared__ float s_best[4];
    __shared__ int   s_bestc[4];
    __shared__ float red[4];
    __shared__ float fin[3][2];

    const int sl  = blockIdx.x;
    const int b   = blockIdx.y;
    const int tid = threadIdx.x;
    const int w   = tid >> 6, lane = tid & 63;
    int* wsi = (int*)ws;
    int* cnt = (int*)ws + OFF_CNT;

    // ---- GT setup: wave w handles row w, lane = class ----
    {
        float v = gt_cls[(b*NN+w)*CC + lane];
        float psum = v;
        float bv = v; int bc = lane;
        #pragma unroll
        for (int off = 32; off > 0; off >>= 1) {
            psum += __shfl_xor(psum, off, 64);
            float ov = __shfl_xor(bv, off, 64);
            int   oc = __shfl_xor(bc, off, 64);
            if (ov > bv || (ov == bv && oc < bc)) { bv = ov; bc = oc; }
        }
        if (lane == 0) {
            s_cls[w] = bc;
            s_pos[w] = fmaxf(psum, 1.f);
            float g0 = gt_loc[(b*NN+w)*DD+0];
            float g1 = gt_loc[(b*NN+w)*DD+1];
            float g2 = gt_loc[(b*NN+w)*DD+2];
            float inv = 1.f / fmaxf(sqrtf(g0*g0 + g1*g1 + g2*g2), 1e-8f);
            s_vt[w][0] = g0*inv; s_vt[w][1] = g1*inv; s_vt[w][2] = g2*inv;
        }
    }
    __syncthreads();

    // ---- cost (fast math) + obj base (accurate) ----
    const int k = sl*KS + tid;
    float l0 = loc_out[((size_t)b*KK+k)*DD+0];
    float l1 = loc_out[((size_t)b*KK+k)*DD+1];
    float l2 = loc_out[((size_t)b*KK+k)*DD+2];
    float inv = 1.f / fmaxf(sqrtf(l0*l0 + l1*l1 + l2*l2), 1e-8f);
    float v0 = l0*inv, v1 = l1*inv, v2 = l2*inv;
    float x = obj_logit[b*KK+k];
    float obj_base = fmaxf(x, 0.f) + log1pf(expf(-fabsf(x)));   // LOSS: accurate
    float oc = -0.1f / (1.f + __expf(-x));                      // cost: fast
    #pragma unroll
    for (int n = 0; n < NN; ++n) {
        float cosv = v0*s_vt[n][0] + v1*s_vt[n][1] + v2*s_vt[n][2];
        cosv = fminf(fmaxf(cosv, -1.f + 1e-6f), 1.f - 1e-6f);
        float loc_c = acospi_fast(cosv);
        float z = cls_logit[((size_t)b*KK+k)*CC + s_cls[n]];
        float e  = __expf(-fabsf(z));
        float lp = __logf(1.f + e);
        float sp = (z >= 0.f) ? lp : (lp - z);                  // softplus(-z)
        float r1 = 1.f / (1.f + e);
        float sn = (z >= 0.f) ? e*r1 : r1;                      // sigmoid(-z)
        float fp = 0.25f * sp * sn * sn;
        cost[n][tid] = loc_c + 0.25f*(fp / s_pos[n]) + oc;
    }

    // obj partial: wave shfl-sum, 4-wave combine.
    float osum = obj_base;
    #pragma unroll
    for (int off = 32; off > 0; off >>= 1) osum += __shfl_xor(osum, off, 64);
    if (lane == 0) obj_s[w] = osum;
    __syncthreads();

    // ---- per-slice top-4 of row w (wave-synchronous) ----
    {
        float vv[4]; int gi[4];
        #pragma unroll
        for (int j = 0; j < 4; ++j) {
            vv[j] = cost[w][lane + 64*j];
            gi[j] = sl*KS + lane + 64*j;
        }
        float cr_val[NN]; int cr_idx[NN];
        #pragma unroll
        for (int r = 0; r < NN; ++r) {
            float bv = vv[0]; int bi = gi[0];
            #pragma unroll
            for (int j = 1; j < 4; ++j)
                if (vv[j] < bv || (vv[j] == bv && gi[j] < bi)) { bv = vv[j]; bi = gi[j]; }
            #pragma unroll
            for (int off = 32; off > 0; off >>= 1) {
                float ov = __shfl_xor(bv, off, 64);
                int   oi = __shfl_xor(bi, off, 64);
                if (ov < bv || (ov == bv && oi < bi)) { bv = ov; bi = oi; }
            }
            cr_val[r] = bv; cr_idx[r] = bi;
            #pragma unroll
            for (int j = 0; j < 4; ++j) if (gi[j] == bi) vv[j] = INFINITY;
        }
        if (lane == 0) {
            int base = ((b*SL + sl)*NN + w)*NN;
            #pragma unroll
            for (int r = 0; r < NN; ++r) {
                ws[OFF_CVAL + base + r]  = cr_val[r];
                wsi[OFF_CIDX + base + r] = cr_idx[r];
            }
        }
        if (tid == 0)
            ws[OFF_OBJ + b*SL + sl] = obj_s[0] + obj_s[1] + obj_s[2] + obj_s[3];
    }

    // ---- batch completion: last slice-block of batch b proceeds ----
    __threadfence();
    if (tid == 0) s_flag = (atomicAdd(&cnt[b], 1) == SL-1);
    __syncthreads();
    if (!s_flag) return;
    __threadfence();

    // ---- merge: wave w holds 32 candidates of row w in lanes 0..31 ----
    {
        float v = INFINITY; int idx = INT_MAX;
        if (lane < SL*NN) {
            int sl2 = lane >> 2, r = lane & 3;
            int base = ((b*SL + sl2)*NN + w)*NN + r;
            v   = ws[OFF_CVAL + base];
            idx = wsi[OFF_CIDX + base];
        }
        #pragma unroll
        for (int r = 0; r < NN; ++r) {
            float bv = v; int bi = idx;
            #pragma unroll
            for (int off = 32; off > 0; off >>= 1) {
                float ov = __shfl_xor(bv, off, 64);
                int   oi = __shfl_xor(bi, off, 64);
                if (ov < bv || (ov == bv && oi < bi)) { bv = ov; bi = oi; }
            }
            if (lane == 0) { cand_val[w][r] = bv; cand_idx[w][r] = bi; }
            if (idx == bi) v = INFINITY;
        }
    }
    __syncthreads();

    // ---- brute force: thread tid = combo tid (4x 2-bit fields) ----
    {
        int a0 = (tid >> 6) & 3, a1 = (tid >> 4) & 3, a2 = (tid >> 2) & 3, a3 = tid & 3;
        int c0 = cand_idx[0][a0], c1 = cand_idx[1][a1];
        int c2 = cand_idx[2][a2], c3 = cand_idx[3][a3];
        bool valid = (c0!=c1) & (c0!=c2) & (c0!=c3) & (c1!=c2) & (c1!=c3) & (c2!=c3);
        float t = cand_val[0][a0] + cand_val[1][a1] + cand_val[2][a2] + cand_val[3][a3];
        float bv = valid ? t : INFINITY;
        int   bc = tid;
        #pragma unroll
        for (int off = 32; off > 0; off >>= 1) {
            float ov = __shfl_xor(bv, off, 64);
            int   oc2 = __shfl_xor(bc, off, 64);
            if (ov < bv || (ov == bv && oc2 < bc)) { bv = ov; bc = oc2; }
        }
        if (lane == 0) { s_best[w] = bv; s_bestc[w] = bc; }
    }
    __syncthreads();

    if (tid == 0) {
        float bv = s_best[0]; int bc = s_bestc[0];
        for (int i = 1; i < 4; ++i)
            if (s_best[i] < bv || (s_best[i] == bv && s_bestc[i] < bc)) { bv = s_best[i]; bc = s_bestc[i]; }
        int a0 = (bc >> 6) & 3, a1 = (bc >> 4) & 3, a2 = (bc >> 2) & 3, a3 = bc & 3;
        s_pred[0] = cand_idx[0][a0]; s_pred[1] = cand_idx[1][a1];
        s_pred[2] = cand_idx[2][a2]; s_pred[3] = cand_idx[3][a3];
        // obj partial
        float om = 0.f;
        for (int sl2 = 0; sl2 < SL; ++sl2) om += ws[OFF_OBJ + b*SL + sl2];
        for (int n = 0; n < NN; ++n) om -= obj_logit[b*KK + s_pred[n]];
        ws[OFF_PART + b*3 + 2] = om;
        // loc partial (12 terms)
        float s = 0.f;
        for (int n = 0; n < NN; ++n)
            for (int d = 0; d < DD; ++d) {
                float diff = loc_out[((size_t)b*KK + s_pred[n])*DD + d] - gt_loc[(b*NN+n)*DD + d];
                s += diff*diff;
            }
        ws[OFF_PART + b*3 + 0] = s;
    }
    __syncthreads();

    // ---- cls partial (accurate focal BCE); gt_cls is exact one-hot ----
    {
        int n = w, c = lane;
        float z = cls_logit[((size_t)b*KK + s_pred[n])*CC + c];
        float tgt = (c == s_cls[n]) ? 1.f : 0.f;
        float p  = 1.f / (1.f + expf(-z));
        float ce = fmaxf(z, 0.f) - z*tgt + log1pf(expf(-fabsf(z)));
        float pt = p*tgt + (1.f-p)*(1.f-tgt);
        float at = 0.25f*tgt + 0.75f*(1.f-tgt);
        float om1 = 1.f - pt;
        float r = at * ce * om1 * om1;
        #pragma unroll
        for (int off = 32; off > 0; off >>= 1) r += __shfl_xor(r, off, 64);
        if (lane == 0) red[n] = r;
    }
    __syncthreads();
    if (tid == 0) ws[OFF_PART + b*3 + 1] = red[0] + red[1] + red[2] + red[3];

    // ---- global completion: last batch-winner does the final reduce ----
    __threadfence();
    if (tid == 0) s_flag = (atomicAdd(&cnt[BB], 1) == BB-1);
    __syncthreads();
    if (!s_flag) return;
    __threadfence();

    {
        float a = 0.f, bsum = 0.f, c = 0.f;
        if (tid < BB) {
            a    = ws[OFF_PART + tid*3 + 0];
            bsum = ws[OFF_PART + tid*3 + 1];
            c    = ws[OFF_PART + tid*3 + 2];
        }
        #pragma unroll
        for (int off = 32; off > 0; off >>= 1) {
            a    += __shfl_xor(a, off, 64);
            bsum += __shfl_xor(bsum, off, 64);
            c    += __shfl_xor(c, off, 64);
        }
        if (lane == 0 && w < 2) { fin[0][w] = a; fin[1][w] = bsum; fin[2][w] = c; }
    }
    __syncthreads();
    if (tid == 0) {
        out[0] = (fin[0][0]+fin[0][1]) / (float)(BB*NN*DD)
               + (fin[1][0]+fin[1][1]) / (float)(BB*NN*CC)
               + (fin[2][0]+fin[2][1]) / (float)(BB*KK);
    }
}

extern "C" void kernel_launch(void* const* d_in, const int* in_sizes, int n_in,
                              void* d_out, int out_size, void* d_ws, size_t ws_size,
                              hipStream_t stream) {
    const float* loc_out   = (const float*)d_in[0];
    const float* obj_logit = (const float*)d_in[1];
    const float* cls_logit = (const float*)d_in[2];
    const float* gt_loc    = (const float*)d_in[3];
    const float* gt_cls    = (const float*)d_in[4];
    float* ws  = (float*)d_ws;
    float* out = (float*)d_out;

    // Zero the completion counters (graph-capture-safe async memset, 516 B).
    hipMemsetAsync((char*)d_ws + OFF_CNT*sizeof(float), 0, (BB+1)*sizeof(int), stream);

    hipLaunchKernelGGL(crit_fused, dim3(SL, BB), dim3(THREADS), 0, stream,
                       loc_out, obj_logit, cls_logit, gt_loc, gt_cls, ws, out);
}

// Round 5
// 28.391 us; speedup vs baseline: 7.8252x; 7.8252x over previous
//
#include <hip/hip_runtime.h>
#include <math.h>
#include <limits.h>

#define BB 128
#define KK 2048
#define NN 4
#define CC 64
#define DD 3
#define SL 8            // K-slices per batch
#define KS (KK/SL)      // 256 k per slice
#define THREADS 256

// ws layout (float words):
#define OFF_CVAL 0
#define OFF_CIDX (BB*SL*NN*NN)
#define OFF_OBJ  (2*BB*SL*NN*NN)
#define OFF_PART (OFF_OBJ + BB*SL)

// ---- fast approximations: COST MATRIX ONLY (losses use accurate libm) ----
__device__ __forceinline__ float acospi_fast(float x) {
    // Hastings: acos(x) ~ sqrt(1-x)*p(x), abs err ~6.7e-5 rad; divided by pi.
    float ax = fabsf(x);
    float p = ((-0.0187293f*ax + 0.0742610f)*ax - 0.2121144f)*ax + 1.5707288f;
    float r = sqrtf(1.f - ax) * p;
    r = (x >= 0.f) ? r : 3.14159274f - r;
    return r * 0.31830988618379067f;
}

// ---------------- Kernel A: cost + per-slice top-4 per GT row ----------------
__global__ void __launch_bounds__(THREADS)
crit_cost(const float* __restrict__ loc_out, const float* __restrict__ obj_logit,
          const float* __restrict__ cls_logit, const float* __restrict__ gt_loc,
          const float* __restrict__ gt_cls, float* __restrict__ ws)
{
    __shared__ float cost[NN][KS];     // 4 KB
    __shared__ float obj_s[4];

    const int sl  = blockIdx.x;
    const int b   = blockIdx.y;
    const int tid = threadIdx.x;
    const int w   = tid >> 6, lane = tid & 63;
    const int k   = sl*KS + tid;

    // ---- issue primary loads early ----
    const float* lp = loc_out + ((size_t)b*KK + k)*DD;
    float l0 = lp[0], l1 = lp[1], l2 = lp[2];
    float x  = obj_logit[b*KK + k];

    // ---- sync-free GT class setup: gt_cls is exact one-hot, CC == 64 lanes ----
    int   cls[NN]; float posin[NN];
    #pragma unroll
    for (int n = 0; n < NN; ++n) {
        float v = gt_cls[(b*NN+n)*CC + lane];
        unsigned long long m = __ballot(v > 0.5f);
        cls[n]   = __ffsll((unsigned long long)m) - 1;
        posin[n] = 1.f / fmaxf((float)__popcll(m), 1.f);
    }

    // ---- issue the 4 strided cls gathers ASAP (the latency hog) ----
    float z[NN];
    #pragma unroll
    for (int n = 0; n < NN; ++n)
        z[n] = cls_logit[((size_t)b*KK + k)*CC + cls[n]];

    // ---- gt vectors: uniform-address scalar loads, computed per-thread ----
    float vt[NN][DD];
    #pragma unroll
    for (int n = 0; n < NN; ++n) {
        float g0 = gt_loc[(b*NN+n)*DD+0];
        float g1 = gt_loc[(b*NN+n)*DD+1];
        float g2 = gt_loc[(b*NN+n)*DD+2];
        float gin = 1.f / fmaxf(sqrtf(g0*g0 + g1*g1 + g2*g2), 1e-8f);
        vt[n][0] = g0*gin; vt[n][1] = g1*gin; vt[n][2] = g2*gin;
    }

    // ---- math (overlaps with in-flight gathers) ----
    float inv = 1.f / fmaxf(sqrtf(l0*l0 + l1*l1 + l2*l2), 1e-8f);
    float v0 = l0*inv, v1 = l1*inv, v2 = l2*inv;
    float obj_base = fmaxf(x, 0.f) + log1pf(expf(-fabsf(x)));   // LOSS: accurate
    float oc = -0.1f / (1.f + __expf(-x));                      // cost: fast
    #pragma unroll
    for (int n = 0; n < NN; ++n) {
        float cosv = v0*vt[n][0] + v1*vt[n][1] + v2*vt[n][2];
        cosv = fminf(fmaxf(cosv, -1.f + 1e-6f), 1.f - 1e-6f);
        float loc_c = acospi_fast(cosv);
        float zz = z[n];
        float e  = __expf(-fabsf(zz));
        float lg = __logf(1.f + e);
        float sp = (zz >= 0.f) ? lg : (lg - zz);                // softplus(-z)
        float r1 = 1.f / (1.f + e);
        float sn = (zz >= 0.f) ? e*r1 : r1;                     // sigmoid(-z)
        float fp = 0.25f * sp * sn * sn;
        cost[n][tid] = loc_c + 0.25f*fp*posin[n] + oc;
    }

    // obj partial: wave shfl-sum, 4-wave combine.
    float osum = obj_base;
    #pragma unroll
    for (int off = 32; off > 0; off >>= 1) osum += __shfl_xor(osum, off, 64);
    if (lane == 0) obj_s[w] = osum;
    __syncthreads();   // cost[][] + obj_s visible

    // ---- per-slice top-4 of row w (wave-synchronous) ----
    float vv[4]; int gi[4];
    #pragma unroll
    for (int j = 0; j < 4; ++j) {
        vv[j] = cost[w][lane + 64*j];
        gi[j] = sl*KS + lane + 64*j;
    }
    float cr_val[NN]; int cr_idx[NN];
    #pragma unroll
    for (int r = 0; r < NN; ++r) {
        float bv = vv[0]; int bi = gi[0];
        #pragma unroll
        for (int j = 1; j < 4; ++j)
            if (vv[j] < bv || (vv[j] == bv && gi[j] < bi)) { bv = vv[j]; bi = gi[j]; }
        #pragma unroll
        for (int off = 32; off > 0; off >>= 1) {
            float ov = __shfl_xor(bv, off, 64);
            int   oi = __shfl_xor(bi, off, 64);
            if (ov < bv || (ov == bv && oi < bi)) { bv = ov; bi = oi; }
        }
        cr_val[r] = bv; cr_idx[r] = bi;
        #pragma unroll
        for (int j = 0; j < 4; ++j) if (gi[j] == bi) vv[j] = INFINITY;
    }
    if (lane == 0) {
        int base = ((b*SL + sl)*NN + w)*NN;
        int* wsi = (int*)ws;
        #pragma unroll
        for (int r = 0; r < NN; ++r) {
            ws[OFF_CVAL + base + r]  = cr_val[r];
            wsi[OFF_CIDX + base + r] = cr_idx[r];
        }
    }
    if (tid == 0)
        ws[OFF_OBJ + b*SL + sl] = obj_s[0] + obj_s[1] + obj_s[2] + obj_s[3];
}

// ---------------- Kernel B: merge candidates, assign, loss partials ----------------
__global__ void __launch_bounds__(THREADS)
crit_match(const float* __restrict__ loc_out, const float* __restrict__ obj_logit,
           const float* __restrict__ cls_logit, const float* __restrict__ gt_loc,
           const float* __restrict__ gt_cls, float* __restrict__ ws)
{
    __shared__ float cand_val[NN][NN];
    __shared__ int   cand_idx[NN][NN];
    __shared__ int   s_pred[NN];
    __shared__ float s_best[4];
    __shared__ int   s_bestc[4];
    __shared__ float red[4];

    const int b = blockIdx.x, tid = threadIdx.x;
    const int w = tid >> 6, lane = tid & 63;
    const int* wsi = (const int*)ws;

    // Merge: wave w holds the 32 candidates of row w in lanes 0..31.
    {
        float v = INFINITY; int idx = INT_MAX;
        if (lane < SL*NN) {
            int sl = lane >> 2, r = lane & 3;
            int base = ((b*SL + sl)*NN + w)*NN + r;
            v   = ws[OFF_CVAL + base];
            idx = wsi[OFF_CIDX + base];
        }
        #pragma unroll
        for (int r = 0; r < NN; ++r) {
            float bv = v; int bi = idx;
            #pragma unroll
            for (int off = 32; off > 0; off >>= 1) {
                float ov = __shfl_xor(bv, off, 64);
                int   oi = __shfl_xor(bi, off, 64);
                if (ov < bv || (ov == bv && oi < bi)) { bv = ov; bi = oi; }
            }
            if (lane == 0) { cand_val[w][r] = bv; cand_idx[w][r] = bi; }
            if (idx == bi) v = INFINITY;   // mask winner
        }
    }
    __syncthreads();

    // Brute force: thread tid evaluates combo tid (a0..a3 = 2-bit fields).
    {
        int a0 = (tid >> 6) & 3, a1 = (tid >> 4) & 3, a2 = (tid >> 2) & 3, a3 = tid & 3;
        int c0 = cand_idx[0][a0], c1 = cand_idx[1][a1];
        int c2 = cand_idx[2][a2], c3 = cand_idx[3][a3];
        bool valid = (c0!=c1) & (c0!=c2) & (c0!=c3) & (c1!=c2) & (c1!=c3) & (c2!=c3);
        float t = cand_val[0][a0] + cand_val[1][a1] + cand_val[2][a2] + cand_val[3][a3];
        float bv = valid ? t : INFINITY;
        int   bc = tid;
        #pragma unroll
        for (int off = 32; off > 0; off >>= 1) {
            float ov = __shfl_xor(bv, off, 64);
            int   oc = __shfl_xor(bc, off, 64);
            if (ov < bv || (ov == bv && oc < bc)) { bv = ov; bc = oc; }
        }
        if (lane == 0) { s_best[w] = bv; s_bestc[w] = bc; }
    }
    __syncthreads();

    if (tid == 0) {
        float bv = s_best[0]; int bc = s_bestc[0];
        for (int i = 1; i < 4; ++i)
            if (s_best[i] < bv || (s_best[i] == bv && s_bestc[i] < bc)) { bv = s_best[i]; bc = s_bestc[i]; }
        int a0 = (bc >> 6) & 3, a1 = (bc >> 4) & 3, a2 = (bc >> 2) & 3, a3 = bc & 3;
        s_pred[0] = cand_idx[0][a0]; s_pred[1] = cand_idx[1][a1];
        s_pred[2] = cand_idx[2][a2]; s_pred[3] = cand_idx[3][a3];

        float om = 0.f;
        for (int sl = 0; sl < SL; ++sl) om += ws[OFF_OBJ + b*SL + sl];
        for (int n = 0; n < NN; ++n) om -= obj_logit[b*KK + s_pred[n]];
        ws[OFF_PART + b*3 + 2] = om;

        float s = 0.f;
        for (int n = 0; n < NN; ++n)
            for (int d = 0; d < DD; ++d) {
                float diff = loc_out[((size_t)b*KK + s_pred[n])*DD + d] - gt_loc[(b*NN+n)*DD + d];
                s += diff*diff;
            }
        ws[OFF_PART + b*3 + 0] = s;
    }
    __syncthreads();

    // cls partial: 256 threads = 4 rows x 64 classes; accurate focal BCE.
    {
        int n = w, c = lane;
        float zz = cls_logit[((size_t)b*KK + s_pred[n])*CC + c];
        float tgt = gt_cls[(b*NN+n)*CC + c];
        float p  = 1.f / (1.f + expf(-zz));
        float ce = fmaxf(zz, 0.f) - zz*tgt + log1pf(expf(-fabsf(zz)));
        float pt = p*tgt + (1.f-p)*(1.f-tgt);
        float at = 0.25f*tgt + 0.75f*(1.f-tgt);
        float om1 = 1.f - pt;
        float r = at * ce * om1 * om1;
        #pragma unroll
        for (int off = 32; off > 0; off >>= 1) r += __shfl_xor(r, off, 64);
        if (lane == 0) red[n] = r;
    }
    __syncthreads();
    if (tid == 0) ws[OFF_PART + b*3 + 1] = red[0] + red[1] + red[2] + red[3];
}

// ---------------- Kernel C: deterministic final reduction ----------------
__global__ void __launch_bounds__(BB)
crit_final(const float* __restrict__ ws, float* __restrict__ out)
{
    __shared__ float s2[3][2];
    int t = threadIdx.x;
    int w = t >> 6, lane = t & 63;
    float a = ws[OFF_PART + t*3+0];
    float b = ws[OFF_PART + t*3+1];
    float c = ws[OFF_PART + t*3+2];
    #pragma unroll
    for (int off = 32; off > 0; off >>= 1) {
        a += __shfl_xor(a, off, 64);
        b += __shfl_xor(b, off, 64);
        c += __shfl_xor(c, off, 64);
    }
    if (lane == 0) { s2[0][w] = a; s2[1][w] = b; s2[2][w] = c; }
    __syncthreads();
    if (t == 0) {
        out[0] = (s2[0][0]+s2[0][1]) / (float)(BB*NN*DD)
               + (s2[1][0]+s2[1][1]) / (float)(BB*NN*CC)
               + (s2[2][0]+s2[2][1]) / (float)(BB*KK);
    }
}

extern "C" void kernel_launch(void* const* d_in, const int* in_sizes, int n_in,
                              void* d_out, int out_size, void* d_ws, size_t ws_size,
                              hipStream_t stream) {
    const float* loc_out   = (const float*)d_in[0];
    const float* obj_logit = (const float*)d_in[1];
    const float* cls_logit = (const float*)d_in[2];
    const float* gt_loc    = (const float*)d_in[3];
    const float* gt_cls    = (const float*)d_in[4];
    float* ws  = (float*)d_ws;
    float* out = (float*)d_out;

    hipLaunchKernelGGL(crit_cost, dim3(SL, BB), dim3(THREADS), 0, stream,
                       loc_out, obj_logit, cls_logit, gt_loc, gt_cls, ws);
    hipLaunchKernelGGL(crit_match, dim3(BB), dim3(THREADS), 0, stream,
                       loc_out, obj_logit, cls_logit, gt_loc, gt_cls, ws);
    hipLaunchKernelGGL(crit_final, dim3(1), dim3(BB), 0, stream, ws, out);
}